// Round 6
// baseline (421.645 us; speedup 1.0000x reference)
//
#include <hip/hip_runtime.h>
#include <hip/hip_bf16.h>

// WeightedLoss round 6: round-5 structure (materialize fp16 sim/eud tiles in
// pass A, stream in pass B) + two fixes:
//  1. NON-TEMPORAL stores/loads for the 133 MB tile stream — round 5's stores
//     evicted the 6 MB inputs from L2/L3 (stats FETCH_SIZE 69 MB for 6 MB of
//     data -> latency-bound gram).
//  2. Vectorized tile layout: u32 slot = t*8192 + tid*32 + pp so pass A writes
//     uint4s and pass B reads contiguous dwordx4 (was scalar u32 @ 1KB stride).
// ws layout:
//   [0]          Ob  bf16 8192x256  (4 MB)
//   [4194304]    Ln  bf16 8192x128  (2 MB)
//   [6291456]    sq  f32 8192
//   [6324224]    pos_sums f32 8192
//   [6356992]    neg_sums f32 8192
//   [6389760]    stats u32[3]
//   [6389824]    simT fp16 tri-packed 2080 tiles x 16384    (68.2 MB)
//   [74547264]   eudT fp16, same layout                     (68.2 MB)

#define B_N 8192
#define NT   64
#define TILE 128
#define NTRI 2080
#define WS_NEEDED 142704704ull

typedef __attribute__((ext_vector_type(8))) short bf16x8;
typedef __attribute__((ext_vector_type(4))) float f32x4;
typedef __attribute__((ext_vector_type(2))) _Float16 f16x2;
typedef __attribute__((ext_vector_type(4))) unsigned u32x4;

__device__ __forceinline__ unsigned fenc(float f) {
    unsigned u = __float_as_uint(f);
    return (u & 0x80000000u) ? ~u : (u | 0x80000000u);
}
__device__ __forceinline__ float fdec(unsigned k) {
    unsigned u = (k & 0x80000000u) ? (k ^ 0x80000000u) : ~k;
    return __uint_as_float(u);
}
__device__ __forceinline__ unsigned pack2(float a, float b) {
    f16x2 p; p[0] = (_Float16)a; p[1] = (_Float16)b;
    return *(unsigned*)&p;
}

// XCD-swizzled upper-tri decode: blocks congruent mod 8 (same XCD) get a
// contiguous tri range -> compact bi band per XCD.
__device__ __forceinline__ int tri_decode_swz(int b, int& bi, int& bj) {
    int t = (b & 7) * (NTRI / 8) + (b >> 3);
    int i = 0, rem = t;
    while (rem >= NT - i) { rem -= NT - i; i++; }
    bi = i; bj = i + rem;
    return t;
}

// ---------------------------------------------------------------- prep ----
__global__ __launch_bounds__(256) void prep_kernel(
    const float* __restrict__ outputs, const float* __restrict__ labels,
    __hip_bfloat16* __restrict__ Ob, __hip_bfloat16* __restrict__ Ln,
    float* __restrict__ sq, float* __restrict__ pos_sums,
    float* __restrict__ neg_sums, unsigned* __restrict__ stats) {
    int w = threadIdx.x >> 6, lane = threadIdx.x & 63;
    int r = blockIdx.x * 4 + w;
    f32x4 v = ((const f32x4*)outputs)[r * 64 + lane];
    float s = v[0]*v[0] + v[1]*v[1] + v[2]*v[2] + v[3]*v[3];
    #pragma unroll
    for (int m = 1; m < 64; m <<= 1) s += __shfl_xor(s, m);
    if (lane == 0) { sq[r] = s; pos_sums[r] = 0.f; neg_sums[r] = 0.f; }
    __hip_bfloat16 o4[4];
    #pragma unroll
    for (int i = 0; i < 4; i++) o4[i] = __float2bfloat16(v[i]);
    *(uint2*)&Ob[(size_t)r * 256 + lane * 4] = *(uint2*)o4;

    float2 lv = ((const float2*)labels)[r * 64 + lane];
    float ls = lv.x * lv.x + lv.y * lv.y;
    #pragma unroll
    for (int m = 1; m < 64; m <<= 1) ls += __shfl_xor(ls, m);
    float nrm = sqrtf(ls) + 1e-12f;
    __hip_bfloat16 l2[2] = { __float2bfloat16(lv.x / nrm),
                             __float2bfloat16(lv.y / nrm) };
    *(unsigned*)&Ln[(size_t)r * 128 + lane * 2] = *(unsigned*)l2;

    if (blockIdx.x == 0 && threadIdx.x == 0) {
        stats[0] = 0xFFFFFFFFu; stats[1] = 0u; stats[2] = 0u;
    }
}

// ------------------------------------------- direct-global 64x64 gram ----
template<int KDIM>
__device__ __forceinline__ void gram64(
    const __hip_bfloat16* __restrict__ X, int rowBase, int colBase,
    int l15, int quad, f32x4 (&acc)[4][4]) {
    const bf16x8* pa[4];
    const bf16x8* pb[4];
    #pragma unroll
    for (int mi = 0; mi < 4; mi++)
        pa[mi] = (const bf16x8*)(X + (size_t)(rowBase + mi * 16 + l15) * KDIM + quad * 8);
    #pragma unroll
    for (int ni = 0; ni < 4; ni++)
        pb[ni] = (const bf16x8*)(X + (size_t)(colBase + ni * 16 + l15) * KDIM + quad * 8);
    #pragma unroll
    for (int mi = 0; mi < 4; mi++)
        #pragma unroll
        for (int ni = 0; ni < 4; ni++) {
            f32x4 z = {0.f, 0.f, 0.f, 0.f};
            acc[mi][ni] = z;
        }
    #pragma unroll
    for (int k0 = 0; k0 < KDIM; k0 += 32) {
        bf16x8 a[4], b[4];
        #pragma unroll
        for (int mi = 0; mi < 4; mi++) a[mi] = pa[mi][k0 >> 3];
        #pragma unroll
        for (int ni = 0; ni < 4; ni++) b[ni] = pb[ni][k0 >> 3];
        #pragma unroll
        for (int mi = 0; mi < 4; mi++)
            #pragma unroll
            for (int ni = 0; ni < 4; ni++)
                acc[mi][ni] = __builtin_amdgcn_mfma_f32_16x16x32_bf16(
                    a[mi], b[ni], acc[mi][ni], 0, 0, 0);
    }
}

// ---------------------------------------------------------------- stats ----
// Grams once; tracks min/max of sim + max of d2; materializes fp16 sim/eud
// tiles via NON-TEMPORAL uint4 stores (don't evict the 6 MB inputs from L2).
// u32 slot = t*8192 + tid*32 + pp, pp = mi*8 + ni*2 + h; u32 packs rows
// (2h, 2h+1) at col (wn+ni*16+l15), rows offset wm+mi*16+quad*4.
__global__ __launch_bounds__(256, 2) void stats_kernel(
    const __hip_bfloat16* __restrict__ Ln, const __hip_bfloat16* __restrict__ Ob,
    const float* __restrict__ sq, unsigned* __restrict__ stats,
    unsigned* __restrict__ simT, unsigned* __restrict__ eudT, int store) {
    int bi, bj;
    int t = tri_decode_swz(blockIdx.x, bi, bj);
    int tid = threadIdx.x, lane = tid & 63, wid = tid >> 6;
    int wm = (wid >> 1) * 64, wn = (wid & 1) * 64;
    int l15 = lane & 15, quad = lane >> 4;
    int rowBase = bi * TILE + wm, colBase = bj * TILE + wn;
    size_t tb = (size_t)t * 8192 + (size_t)tid * 32;

    float lmin = 1e30f, lmax = -1e30f, dmax = 0.f;
    f32x4 acc[4][4];

    gram64<128>(Ln, rowBase, colBase, l15, quad, acc);
    #pragma unroll
    for (int mi = 0; mi < 4; mi++) {
        u32x4 v0, v1;
        #pragma unroll
        for (int ni = 0; ni < 4; ni++)
            #pragma unroll
            for (int h = 0; h < 2; h++) {
                float s0 = acc[mi][ni][2 * h], s1 = acc[mi][ni][2 * h + 1];
                lmin = fminf(lmin, fminf(s0, s1));
                lmax = fmaxf(lmax, fmaxf(s0, s1));
                int j = ni * 2 + h;
                unsigned pk = pack2(s0, s1);
                if (j < 4) v0[j] = pk; else v1[j - 4] = pk;
            }
        if (store) {
            u32x4* p = (u32x4*)(simT + tb + mi * 8);
            __builtin_nontemporal_store(v0, p);
            __builtin_nontemporal_store(v1, p + 1);
        }
    }

    gram64<256>(Ob, rowBase, colBase, l15, quad, acc);
    float sqj[4];
    #pragma unroll
    for (int ni = 0; ni < 4; ni++) sqj[ni] = sq[colBase + ni * 16 + l15];
    #pragma unroll
    for (int mi = 0; mi < 4; mi++) {
        f32x4 sqi = *(const f32x4*)&sq[rowBase + mi * 16 + quad * 4];
        u32x4 v0, v1;
        #pragma unroll
        for (int ni = 0; ni < 4; ni++)
            #pragma unroll
            for (int h = 0; h < 2; h++) {
                float d20 = fmaxf(sqi[2*h]   + sqj[ni] - 2.f * acc[mi][ni][2*h],   0.f);
                float d21 = fmaxf(sqi[2*h+1] + sqj[ni] - 2.f * acc[mi][ni][2*h+1], 0.f);
                dmax = fmaxf(dmax, fmaxf(d20, d21));
                float e0 = (d20 > 0.f) ? sqrtf(d20) : 0.f;
                float e1 = (d21 > 0.f) ? sqrtf(d21) : 0.f;
                int j = ni * 2 + h;
                unsigned pk = pack2(e0, e1);
                if (j < 4) v0[j] = pk; else v1[j - 4] = pk;
            }
        if (store) {
            u32x4* p = (u32x4*)(eudT + tb + mi * 8);
            __builtin_nontemporal_store(v0, p);
            __builtin_nontemporal_store(v1, p + 1);
        }
    }

    #pragma unroll
    for (int m = 1; m < 64; m <<= 1) {
        lmin = fminf(lmin, __shfl_xor(lmin, m));
        lmax = fmaxf(lmax, __shfl_xor(lmax, m));
        dmax = fmaxf(dmax, __shfl_xor(dmax, m));
    }
    __shared__ float red[3][4];
    if ((tid & 63) == 0) { red[0][wid] = lmin; red[1][wid] = lmax; red[2][wid] = dmax; }
    __syncthreads();
    if (tid == 0) {
        lmin = fminf(fminf(red[0][0], red[0][1]), fminf(red[0][2], red[0][3]));
        lmax = fmaxf(fmaxf(red[1][0], red[1][1]), fmaxf(red[1][2], red[1][3]));
        dmax = fmaxf(fmaxf(red[2][0], red[2][1]), fmaxf(red[2][2], red[2][3]));
        atomicMin(&stats[0], fenc(lmin));
        atomicMax(&stats[1], fenc(lmax));
        atomicMax(&stats[2], fenc(dmax));
    }
}

// ----------------------------------------------------------- loss stream ----
// Pure streaming epilogue: NT dwordx4 reads of the fp16 tiles, exp terms,
// row+col sums, one atomic per row per block.
__global__ __launch_bounds__(256) void loss_stream_kernel(
    const unsigned* __restrict__ simT, const unsigned* __restrict__ eudT,
    const unsigned* __restrict__ stats,
    float* __restrict__ pos_sums, float* __restrict__ neg_sums) {
    int bi, bj;
    int t = tri_decode_swz(blockIdx.x, bi, bj);
    int tid = threadIdx.x, lane = tid & 63, wid = tid >> 6;
    int wm = (wid >> 1) * 64, wn = (wid & 1) * 64;
    int l15 = lane & 15, quad = lane >> 4;
    size_t tb = (size_t)t * 8192 + (size_t)tid * 32;

    float smin = fdec(stats[0]);
    float smax = fdec(stats[1]);
    float d2max = fdec(stats[2]);
    float invr = 1.f / (smax - smin);
    float invem = rsqrtf(d2max);

    __shared__ float rP[TILE][2], rN[TILE][2];
    __shared__ float cP[TILE][2], cN[TILE][2];
    float cpsum[4] = {0.f, 0.f, 0.f, 0.f};
    float cnsum[4] = {0.f, 0.f, 0.f, 0.f};

    #pragma unroll
    for (int mi = 0; mi < 4; mi++) {
        const u32x4* sp = (const u32x4*)(simT + tb + mi * 8);
        const u32x4* ep = (const u32x4*)(eudT + tb + mi * 8);
        u32x4 s0 = __builtin_nontemporal_load(sp);
        u32x4 s1 = __builtin_nontemporal_load(sp + 1);
        u32x4 e0 = __builtin_nontemporal_load(ep);
        u32x4 e1 = __builtin_nontemporal_load(ep + 1);
        float ps[4] = {0.f, 0.f, 0.f, 0.f};   // rows quad*4 + {0,1,2,3}
        float ns[4] = {0.f, 0.f, 0.f, 0.f};
        #pragma unroll
        for (int j = 0; j < 8; j++) {
            unsigned sv = (j < 4) ? s0[j] : s1[j - 4];
            unsigned ev = (j < 4) ? e0[j] : e1[j - 4];
            int ni = j >> 1, h = j & 1;
            f16x2 spair = *(f16x2*)&sv;
            f16x2 epair = *(f16x2*)&ev;
            #pragma unroll
            for (int e = 0; e < 2; e++) {
                float sn = ((float)spair[e] - smin) * invr;
                float dist = (float)epair[e] * invem + sn;
                bool pos = sn > 0.5f;   // TAU
                float pv = pos ? __expf(dist) : 0.f;
                float nv = pos ? 0.f : __expf(1.0f - dist);  // MAG = 1
                ps[2 * h + e] += pv;  ns[2 * h + e] += nv;
                cpsum[ni] += pv;  cnsum[ni] += nv;
            }
        }
        #pragma unroll
        for (int r = 0; r < 4; r++) {
            #pragma unroll
            for (int m = 1; m < 16; m <<= 1) {
                ps[r] += __shfl_xor(ps[r], m);
                ns[r] += __shfl_xor(ns[r], m);
            }
            if (l15 == 0) {
                int rr = wm + mi * 16 + quad * 4 + r;
                rP[rr][wid & 1] = ps[r];
                rN[rr][wid & 1] = ns[r];
            }
        }
    }
    #pragma unroll
    for (int ni = 0; ni < 4; ni++) {
        #pragma unroll
        for (int m = 16; m < 64; m <<= 1) {
            cpsum[ni] += __shfl_xor(cpsum[ni], m);
            cnsum[ni] += __shfl_xor(cnsum[ni], m);
        }
        if (quad == 0) {
            int cc = wn + ni * 16 + l15;
            cP[cc][wid >> 1] = cpsum[ni];
            cN[cc][wid >> 1] = cnsum[ni];
        }
    }
    __syncthreads();
    if (tid < TILE) {
        atomicAdd(&pos_sums[bi * TILE + tid], rP[tid][0] + rP[tid][1]);
        atomicAdd(&neg_sums[bi * TILE + tid], rN[tid][0] + rN[tid][1]);
        if (bi != bj) {
            atomicAdd(&pos_sums[bj * TILE + tid], cP[tid][0] + cP[tid][1]);
            atomicAdd(&neg_sums[bj * TILE + tid], cN[tid][0] + cN[tid][1]);
        }
    }
}

// ------------------------------------------------ loss fallback (recompute) ----
__global__ __launch_bounds__(256, 2) void loss_recompute_kernel(
    const __hip_bfloat16* __restrict__ Ln, const __hip_bfloat16* __restrict__ Ob,
    const float* __restrict__ sq, const unsigned* __restrict__ stats,
    float* __restrict__ pos_sums, float* __restrict__ neg_sums) {
    int bi, bj;
    tri_decode_swz(blockIdx.x, bi, bj);
    int tid = threadIdx.x, lane = tid & 63, wid = tid >> 6;
    int wm = (wid >> 1) * 64, wn = (wid & 1) * 64;
    int l15 = lane & 15, quad = lane >> 4;
    int rowBase = bi * TILE + wm, colBase = bj * TILE + wn;

    f32x4 accS[4][4], accG[4][4];
    gram64<128>(Ln, rowBase, colBase, l15, quad, accS);
    gram64<256>(Ob, rowBase, colBase, l15, quad, accG);

    float smin = fdec(stats[0]);
    float smax = fdec(stats[1]);
    float d2max = fdec(stats[2]);
    float invr = 1.f / (smax - smin);
    float invem = rsqrtf(d2max);

    __shared__ float rP[TILE][2], rN[TILE][2];
    __shared__ float cP[TILE][2], cN[TILE][2];
    float sqj[4];
    #pragma unroll
    for (int ni = 0; ni < 4; ni++) sqj[ni] = sq[colBase + ni * 16 + l15];
    float cpsum[4] = {0.f, 0.f, 0.f, 0.f};
    float cnsum[4] = {0.f, 0.f, 0.f, 0.f};

    #pragma unroll
    for (int mi = 0; mi < 4; mi++) {
        f32x4 sqi = *(const f32x4*)&sq[rowBase + mi * 16 + quad * 4];
        #pragma unroll
        for (int r = 0; r < 4; r++) {
            float psum = 0.f, nsum = 0.f;
            #pragma unroll
            for (int ni = 0; ni < 4; ni++) {
                float sn = (accS[mi][ni][r] - smin) * invr;
                float d2 = fmaxf(sqi[r] + sqj[ni] - 2.f * accG[mi][ni][r], 0.f);
                float eud = (d2 > 0.f) ? sqrtf(d2) * invem : 0.f;
                float dist = eud + sn;
                bool pos = sn > 0.5f;
                float pv = pos ? __expf(dist) : 0.f;
                float nv = pos ? 0.f : __expf(1.0f - dist);
                psum += pv;  nsum += nv;
                cpsum[ni] += pv;  cnsum[ni] += nv;
            }
            #pragma unroll
            for (int m = 1; m < 16; m <<= 1) {
                psum += __shfl_xor(psum, m);
                nsum += __shfl_xor(nsum, m);
            }
            if (l15 == 0) {
                int rr = wm + mi * 16 + quad * 4 + r;
                rP[rr][wid & 1] = psum;
                rN[rr][wid & 1] = nsum;
            }
        }
    }
    #pragma unroll
    for (int ni = 0; ni < 4; ni++) {
        #pragma unroll
        for (int m = 16; m < 64; m <<= 1) {
            cpsum[ni] += __shfl_xor(cpsum[ni], m);
            cnsum[ni] += __shfl_xor(cnsum[ni], m);
        }
        if (quad == 0) {
            int cc = wn + ni * 16 + l15;
            cP[cc][wid >> 1] = cpsum[ni];
            cN[cc][wid >> 1] = cnsum[ni];
        }
    }
    __syncthreads();
    if (tid < TILE) {
        atomicAdd(&pos_sums[bi * TILE + tid], rP[tid][0] + rP[tid][1]);
        atomicAdd(&neg_sums[bi * TILE + tid], rN[tid][0] + rN[tid][1]);
        if (bi != bj) {
            atomicAdd(&pos_sums[bj * TILE + tid], cP[tid][0] + cP[tid][1]);
            atomicAdd(&neg_sums[bj * TILE + tid], cN[tid][0] + cN[tid][1]);
        }
    }
}

// ------------------------------------------------------------- finalize ----
__global__ __launch_bounds__(256) void finalize_kernel(
    const float* __restrict__ pos_sums, const float* __restrict__ neg_sums,
    float* __restrict__ out) {
    int t = threadIdx.x;
    float acc = 0.f;
    for (int i = t; i < B_N; i += 256) {
        float p = pos_sums[i], n = neg_sums[i];
        float pl = fmaxf(logf(p), 0.f);
        float nl = (n > 0.f) ? fmaxf(logf(n), 0.f) : 0.f;
        acc += pl + nl;
    }
    #pragma unroll
    for (int m = 1; m < 64; m <<= 1) acc += __shfl_xor(acc, m);
    __shared__ float w4[4];
    if ((t & 63) == 0) w4[t >> 6] = acc;
    __syncthreads();
    if (t == 0) out[0] = (w4[0] + w4[1] + w4[2] + w4[3]) / (float)B_N;
}

// ------------------------------------------------------------------ entry ----
extern "C" void kernel_launch(void* const* d_in, const int* in_sizes, int n_in,
                              void* d_out, int out_size, void* d_ws, size_t ws_size,
                              hipStream_t stream) {
    const float* outputs = (const float*)d_in[0];
    const float* labels  = (const float*)d_in[1];
    float* out = (float*)d_out;
    char* ws = (char*)d_ws;
    __hip_bfloat16* Ob = (__hip_bfloat16*)(ws);
    __hip_bfloat16* Ln = (__hip_bfloat16*)(ws + 4194304);
    float* sq          = (float*)(ws + 6291456);
    float* pos_sums    = (float*)(ws + 6324224);
    float* neg_sums    = (float*)(ws + 6356992);
    unsigned* stats    = (unsigned*)(ws + 6389760);
    unsigned* simT     = (unsigned*)(ws + 6389824);
    unsigned* eudT     = (unsigned*)(ws + 74547264);
    int big = (ws_size >= WS_NEEDED) ? 1 : 0;

    prep_kernel<<<B_N / 4, 256, 0, stream>>>(outputs, labels, Ob, Ln, sq,
                                             pos_sums, neg_sums, stats);
    stats_kernel<<<NTRI, 256, 0, stream>>>(Ln, Ob, sq, stats, simT, eudT, big);
    if (big)
        loss_stream_kernel<<<NTRI, 256, 0, stream>>>(simT, eudT, stats,
                                                     pos_sums, neg_sums);
    else
        loss_recompute_kernel<<<NTRI, 256, 0, stream>>>(Ln, Ob, sq, stats,
                                                        pos_sums, neg_sums);
    finalize_kernel<<<1, 256, 0, stream>>>(pos_sums, neg_sums, out);
}

// Round 7
// 254.898 us; speedup vs baseline: 1.6542x; 1.6542x over previous
//
#include <hip/hip_runtime.h>
#include <hip/hip_bf16.h>

// WeightedLoss round 7: fix round-6's store-coalescing bug. Round 6 vectorized
// per-thread (uint4) but put lanes at 128-B stride -> one wave store touched
// 64 cache lines x 16B -> WRITE_SIZE 133->384 MB (partial-line padding) and
// stats 171->259 us. New chunked layout gives BOTH per-lane uint4 AND lane
// contiguity: u32 slot = t*8192 + c*1024 + tid*4, c = mi*2 + half. One wave
// store = 1 KB contiguous full lines. NT stores/loads kept (they did improve
// input L2 residency: FETCH 69->55 MB).
// ws layout:
//   [0]          Ob  bf16 8192x256  (4 MB)
//   [4194304]    Ln  bf16 8192x128  (2 MB)
//   [6291456]    sq  f32 8192
//   [6324224]    pos_sums f32 8192
//   [6356992]    neg_sums f32 8192
//   [6389760]    stats u32[3]
//   [6389824]    simT fp16 tri-packed 2080 tiles x 16384    (68.2 MB)
//   [74547264]   eudT fp16, same layout                     (68.2 MB)

#define B_N 8192
#define NT   64
#define TILE 128
#define NTRI 2080
#define WS_NEEDED 142704704ull

typedef __attribute__((ext_vector_type(8))) short bf16x8;
typedef __attribute__((ext_vector_type(4))) float f32x4;
typedef __attribute__((ext_vector_type(2))) _Float16 f16x2;
typedef __attribute__((ext_vector_type(4))) unsigned u32x4;

__device__ __forceinline__ unsigned fenc(float f) {
    unsigned u = __float_as_uint(f);
    return (u & 0x80000000u) ? ~u : (u | 0x80000000u);
}
__device__ __forceinline__ float fdec(unsigned k) {
    unsigned u = (k & 0x80000000u) ? (k ^ 0x80000000u) : ~k;
    return __uint_as_float(u);
}
__device__ __forceinline__ unsigned pack2(float a, float b) {
    f16x2 p; p[0] = (_Float16)a; p[1] = (_Float16)b;
    return *(unsigned*)&p;
}

// XCD-swizzled upper-tri decode.
__device__ __forceinline__ int tri_decode_swz(int b, int& bi, int& bj) {
    int t = (b & 7) * (NTRI / 8) + (b >> 3);
    int i = 0, rem = t;
    while (rem >= NT - i) { rem -= NT - i; i++; }
    bi = i; bj = i + rem;
    return t;
}

// ---------------------------------------------------------------- prep ----
__global__ __launch_bounds__(256) void prep_kernel(
    const float* __restrict__ outputs, const float* __restrict__ labels,
    __hip_bfloat16* __restrict__ Ob, __hip_bfloat16* __restrict__ Ln,
    float* __restrict__ sq, float* __restrict__ pos_sums,
    float* __restrict__ neg_sums, unsigned* __restrict__ stats) {
    int w = threadIdx.x >> 6, lane = threadIdx.x & 63;
    int r = blockIdx.x * 4 + w;
    f32x4 v = ((const f32x4*)outputs)[r * 64 + lane];
    float s = v[0]*v[0] + v[1]*v[1] + v[2]*v[2] + v[3]*v[3];
    #pragma unroll
    for (int m = 1; m < 64; m <<= 1) s += __shfl_xor(s, m);
    if (lane == 0) { sq[r] = s; pos_sums[r] = 0.f; neg_sums[r] = 0.f; }
    __hip_bfloat16 o4[4];
    #pragma unroll
    for (int i = 0; i < 4; i++) o4[i] = __float2bfloat16(v[i]);
    *(uint2*)&Ob[(size_t)r * 256 + lane * 4] = *(uint2*)o4;

    float2 lv = ((const float2*)labels)[r * 64 + lane];
    float ls = lv.x * lv.x + lv.y * lv.y;
    #pragma unroll
    for (int m = 1; m < 64; m <<= 1) ls += __shfl_xor(ls, m);
    float nrm = sqrtf(ls) + 1e-12f;
    __hip_bfloat16 l2[2] = { __float2bfloat16(lv.x / nrm),
                             __float2bfloat16(lv.y / nrm) };
    *(unsigned*)&Ln[(size_t)r * 128 + lane * 2] = *(unsigned*)l2;

    if (blockIdx.x == 0 && threadIdx.x == 0) {
        stats[0] = 0xFFFFFFFFu; stats[1] = 0u; stats[2] = 0u;
    }
}

// ------------------------------------------- direct-global 64x64 gram ----
template<int KDIM>
__device__ __forceinline__ void gram64(
    const __hip_bfloat16* __restrict__ X, int rowBase, int colBase,
    int l15, int quad, f32x4 (&acc)[4][4]) {
    const bf16x8* pa[4];
    const bf16x8* pb[4];
    #pragma unroll
    for (int mi = 0; mi < 4; mi++)
        pa[mi] = (const bf16x8*)(X + (size_t)(rowBase + mi * 16 + l15) * KDIM + quad * 8);
    #pragma unroll
    for (int ni = 0; ni < 4; ni++)
        pb[ni] = (const bf16x8*)(X + (size_t)(colBase + ni * 16 + l15) * KDIM + quad * 8);
    #pragma unroll
    for (int mi = 0; mi < 4; mi++)
        #pragma unroll
        for (int ni = 0; ni < 4; ni++) {
            f32x4 z = {0.f, 0.f, 0.f, 0.f};
            acc[mi][ni] = z;
        }
    #pragma unroll
    for (int k0 = 0; k0 < KDIM; k0 += 32) {
        bf16x8 a[4], b[4];
        #pragma unroll
        for (int mi = 0; mi < 4; mi++) a[mi] = pa[mi][k0 >> 3];
        #pragma unroll
        for (int ni = 0; ni < 4; ni++) b[ni] = pb[ni][k0 >> 3];
        #pragma unroll
        for (int mi = 0; mi < 4; mi++)
            #pragma unroll
            for (int ni = 0; ni < 4; ni++)
                acc[mi][ni] = __builtin_amdgcn_mfma_f32_16x16x32_bf16(
                    a[mi], b[ni], acc[mi][ni], 0, 0, 0);
    }
}

// ---------------------------------------------------------------- stats ----
// Grams once; min/max of sim + max of d2; materializes fp16 sim/eud tiles.
// Chunked coalesced layout: u32 slot = t*8192 + c*1024 + tid*4, c = mi*2+half.
// Each NT uint4 store: lane-contiguous 1 KB per wave.
__global__ __launch_bounds__(256, 2) void stats_kernel(
    const __hip_bfloat16* __restrict__ Ln, const __hip_bfloat16* __restrict__ Ob,
    const float* __restrict__ sq, unsigned* __restrict__ stats,
    unsigned* __restrict__ simT, unsigned* __restrict__ eudT, int store) {
    int bi, bj;
    int t = tri_decode_swz(blockIdx.x, bi, bj);
    int tid = threadIdx.x, lane = tid & 63, wid = tid >> 6;
    int wm = (wid >> 1) * 64, wn = (wid & 1) * 64;
    int l15 = lane & 15, quad = lane >> 4;
    int rowBase = bi * TILE + wm, colBase = bj * TILE + wn;
    size_t tB = (size_t)t * 8192 + (size_t)tid * 4;

    float lmin = 1e30f, lmax = -1e30f, dmax = 0.f;
    f32x4 acc[4][4];

    gram64<128>(Ln, rowBase, colBase, l15, quad, acc);
    #pragma unroll
    for (int mi = 0; mi < 4; mi++) {
        u32x4 v0, v1;
        #pragma unroll
        for (int ni = 0; ni < 4; ni++)
            #pragma unroll
            for (int h = 0; h < 2; h++) {
                float s0 = acc[mi][ni][2 * h], s1 = acc[mi][ni][2 * h + 1];
                lmin = fminf(lmin, fminf(s0, s1));
                lmax = fmaxf(lmax, fmaxf(s0, s1));
                int j = ni * 2 + h;
                unsigned pk = pack2(s0, s1);
                if (j < 4) v0[j] = pk; else v1[j - 4] = pk;
            }
        if (store) {
            __builtin_nontemporal_store(v0, (u32x4*)(simT + tB + (mi * 2 + 0) * 1024));
            __builtin_nontemporal_store(v1, (u32x4*)(simT + tB + (mi * 2 + 1) * 1024));
        }
    }

    gram64<256>(Ob, rowBase, colBase, l15, quad, acc);
    float sqj[4];
    #pragma unroll
    for (int ni = 0; ni < 4; ni++) sqj[ni] = sq[colBase + ni * 16 + l15];
    #pragma unroll
    for (int mi = 0; mi < 4; mi++) {
        f32x4 sqi = *(const f32x4*)&sq[rowBase + mi * 16 + quad * 4];
        u32x4 v0, v1;
        #pragma unroll
        for (int ni = 0; ni < 4; ni++)
            #pragma unroll
            for (int h = 0; h < 2; h++) {
                float d20 = fmaxf(sqi[2*h]   + sqj[ni] - 2.f * acc[mi][ni][2*h],   0.f);
                float d21 = fmaxf(sqi[2*h+1] + sqj[ni] - 2.f * acc[mi][ni][2*h+1], 0.f);
                dmax = fmaxf(dmax, fmaxf(d20, d21));
                float e0 = (d20 > 0.f) ? sqrtf(d20) : 0.f;
                float e1 = (d21 > 0.f) ? sqrtf(d21) : 0.f;
                int j = ni * 2 + h;
                unsigned pk = pack2(e0, e1);
                if (j < 4) v0[j] = pk; else v1[j - 4] = pk;
            }
        if (store) {
            __builtin_nontemporal_store(v0, (u32x4*)(eudT + tB + (mi * 2 + 0) * 1024));
            __builtin_nontemporal_store(v1, (u32x4*)(eudT + tB + (mi * 2 + 1) * 1024));
        }
    }

    #pragma unroll
    for (int m = 1; m < 64; m <<= 1) {
        lmin = fminf(lmin, __shfl_xor(lmin, m));
        lmax = fmaxf(lmax, __shfl_xor(lmax, m));
        dmax = fmaxf(dmax, __shfl_xor(dmax, m));
    }
    __shared__ float red[3][4];
    if ((tid & 63) == 0) { red[0][wid] = lmin; red[1][wid] = lmax; red[2][wid] = dmax; }
    __syncthreads();
    if (tid == 0) {
        lmin = fminf(fminf(red[0][0], red[0][1]), fminf(red[0][2], red[0][3]));
        lmax = fmaxf(fmaxf(red[1][0], red[1][1]), fmaxf(red[1][2], red[1][3]));
        dmax = fmaxf(fmaxf(red[2][0], red[2][1]), fmaxf(red[2][2], red[2][3]));
        atomicMin(&stats[0], fenc(lmin));
        atomicMax(&stats[1], fenc(lmax));
        atomicMax(&stats[2], fenc(dmax));
    }
}

// ----------------------------------------------------------- loss stream ----
// Pure streaming epilogue: coalesced NT dwordx4 reads, exp terms, row+col
// sums, one atomic per row per block.
__global__ __launch_bounds__(256) void loss_stream_kernel(
    const unsigned* __restrict__ simT, const unsigned* __restrict__ eudT,
    const unsigned* __restrict__ stats,
    float* __restrict__ pos_sums, float* __restrict__ neg_sums) {
    int bi, bj;
    int t = tri_decode_swz(blockIdx.x, bi, bj);
    int tid = threadIdx.x, lane = tid & 63, wid = tid >> 6;
    int wm = (wid >> 1) * 64, wn = (wid & 1) * 64;
    int l15 = lane & 15, quad = lane >> 4;
    size_t tB = (size_t)t * 8192 + (size_t)tid * 4;

    float smin = fdec(stats[0]);
    float smax = fdec(stats[1]);
    float d2max = fdec(stats[2]);
    float invr = 1.f / (smax - smin);
    float invem = rsqrtf(d2max);

    __shared__ float rP[TILE][2], rN[TILE][2];
    __shared__ float cP[TILE][2], cN[TILE][2];
    float cpsum[4] = {0.f, 0.f, 0.f, 0.f};
    float cnsum[4] = {0.f, 0.f, 0.f, 0.f};

    #pragma unroll
    for (int mi = 0; mi < 4; mi++) {
        u32x4 s0 = __builtin_nontemporal_load((const u32x4*)(simT + tB + (mi * 2 + 0) * 1024));
        u32x4 s1 = __builtin_nontemporal_load((const u32x4*)(simT + tB + (mi * 2 + 1) * 1024));
        u32x4 e0 = __builtin_nontemporal_load((const u32x4*)(eudT + tB + (mi * 2 + 0) * 1024));
        u32x4 e1 = __builtin_nontemporal_load((const u32x4*)(eudT + tB + (mi * 2 + 1) * 1024));
        float ps[4] = {0.f, 0.f, 0.f, 0.f};   // rows quad*4 + {0,1,2,3}
        float ns[4] = {0.f, 0.f, 0.f, 0.f};
        #pragma unroll
        for (int j = 0; j < 8; j++) {
            unsigned sv = (j < 4) ? s0[j] : s1[j - 4];
            unsigned ev = (j < 4) ? e0[j] : e1[j - 4];
            int ni = j >> 1, h = j & 1;
            f16x2 spair = *(f16x2*)&sv;
            f16x2 epair = *(f16x2*)&ev;
            #pragma unroll
            for (int e = 0; e < 2; e++) {
                float sn = ((float)spair[e] - smin) * invr;
                float dist = (float)epair[e] * invem + sn;
                bool pos = sn > 0.5f;   // TAU
                float pv = pos ? __expf(dist) : 0.f;
                float nv = pos ? 0.f : __expf(1.0f - dist);  // MAG = 1
                ps[2 * h + e] += pv;  ns[2 * h + e] += nv;
                cpsum[ni] += pv;  cnsum[ni] += nv;
            }
        }
        #pragma unroll
        for (int r = 0; r < 4; r++) {
            #pragma unroll
            for (int m = 1; m < 16; m <<= 1) {
                ps[r] += __shfl_xor(ps[r], m);
                ns[r] += __shfl_xor(ns[r], m);
            }
            if (l15 == 0) {
                int rr = wm + mi * 16 + quad * 4 + r;
                rP[rr][wid & 1] = ps[r];
                rN[rr][wid & 1] = ns[r];
            }
        }
    }
    #pragma unroll
    for (int ni = 0; ni < 4; ni++) {
        #pragma unroll
        for (int m = 16; m < 64; m <<= 1) {
            cpsum[ni] += __shfl_xor(cpsum[ni], m);
            cnsum[ni] += __shfl_xor(cnsum[ni], m);
        }
        if (quad == 0) {
            int cc = wn + ni * 16 + l15;
            cP[cc][wid >> 1] = cpsum[ni];
            cN[cc][wid >> 1] = cnsum[ni];
        }
    }
    __syncthreads();
    if (tid < TILE) {
        atomicAdd(&pos_sums[bi * TILE + tid], rP[tid][0] + rP[tid][1]);
        atomicAdd(&neg_sums[bi * TILE + tid], rN[tid][0] + rN[tid][1]);
        if (bi != bj) {
            atomicAdd(&pos_sums[bj * TILE + tid], cP[tid][0] + cP[tid][1]);
            atomicAdd(&neg_sums[bj * TILE + tid], cN[tid][0] + cN[tid][1]);
        }
    }
}

// ------------------------------------------------ loss fallback (recompute) ----
__global__ __launch_bounds__(256, 2) void loss_recompute_kernel(
    const __hip_bfloat16* __restrict__ Ln, const __hip_bfloat16* __restrict__ Ob,
    const float* __restrict__ sq, const unsigned* __restrict__ stats,
    float* __restrict__ pos_sums, float* __restrict__ neg_sums) {
    int bi, bj;
    tri_decode_swz(blockIdx.x, bi, bj);
    int tid = threadIdx.x, lane = tid & 63, wid = tid >> 6;
    int wm = (wid >> 1) * 64, wn = (wid & 1) * 64;
    int l15 = lane & 15, quad = lane >> 4;
    int rowBase = bi * TILE + wm, colBase = bj * TILE + wn;

    f32x4 accS[4][4], accG[4][4];
    gram64<128>(Ln, rowBase, colBase, l15, quad, accS);
    gram64<256>(Ob, rowBase, colBase, l15, quad, accG);

    float smin = fdec(stats[0]);
    float smax = fdec(stats[1]);
    float d2max = fdec(stats[2]);
    float invr = 1.f / (smax - smin);
    float invem = rsqrtf(d2max);

    __shared__ float rP[TILE][2], rN[TILE][2];
    __shared__ float cP[TILE][2], cN[TILE][2];
    float sqj[4];
    #pragma unroll
    for (int ni = 0; ni < 4; ni++) sqj[ni] = sq[colBase + ni * 16 + l15];
    float cpsum[4] = {0.f, 0.f, 0.f, 0.f};
    float cnsum[4] = {0.f, 0.f, 0.f, 0.f};

    #pragma unroll
    for (int mi = 0; mi < 4; mi++) {
        f32x4 sqi = *(const f32x4*)&sq[rowBase + mi * 16 + quad * 4];
        #pragma unroll
        for (int r = 0; r < 4; r++) {
            float psum = 0.f, nsum = 0.f;
            #pragma unroll
            for (int ni = 0; ni < 4; ni++) {
                float sn = (accS[mi][ni][r] - smin) * invr;
                float d2 = fmaxf(sqi[r] + sqj[ni] - 2.f * accG[mi][ni][r], 0.f);
                float eud = (d2 > 0.f) ? sqrtf(d2) * invem : 0.f;
                float dist = eud + sn;
                bool pos = sn > 0.5f;
                float pv = pos ? __expf(dist) : 0.f;
                float nv = pos ? 0.f : __expf(1.0f - dist);
                psum += pv;  nsum += nv;
                cpsum[ni] += pv;  cnsum[ni] += nv;
            }
            #pragma unroll
            for (int m = 1; m < 16; m <<= 1) {
                psum += __shfl_xor(psum, m);
                nsum += __shfl_xor(nsum, m);
            }
            if (l15 == 0) {
                int rr = wm + mi * 16 + quad * 4 + r;
                rP[rr][wid & 1] = psum;
                rN[rr][wid & 1] = nsum;
            }
        }
    }
    #pragma unroll
    for (int ni = 0; ni < 4; ni++) {
        #pragma unroll
        for (int m = 16; m < 64; m <<= 1) {
            cpsum[ni] += __shfl_xor(cpsum[ni], m);
            cnsum[ni] += __shfl_xor(cnsum[ni], m);
        }
        if (quad == 0) {
            int cc = wn + ni * 16 + l15;
            cP[cc][wid >> 1] = cpsum[ni];
            cN[cc][wid >> 1] = cnsum[ni];
        }
    }
    __syncthreads();
    if (tid < TILE) {
        atomicAdd(&pos_sums[bi * TILE + tid], rP[tid][0] + rP[tid][1]);
        atomicAdd(&neg_sums[bi * TILE + tid], rN[tid][0] + rN[tid][1]);
        if (bi != bj) {
            atomicAdd(&pos_sums[bj * TILE + tid], cP[tid][0] + cP[tid][1]);
            atomicAdd(&neg_sums[bj * TILE + tid], cN[tid][0] + cN[tid][1]);
        }
    }
}

// ------------------------------------------------------------- finalize ----
__global__ __launch_bounds__(256) void finalize_kernel(
    const float* __restrict__ pos_sums, const float* __restrict__ neg_sums,
    float* __restrict__ out) {
    int t = threadIdx.x;
    float acc = 0.f;
    for (int i = t; i < B_N; i += 256) {
        float p = pos_sums[i], n = neg_sums[i];
        float pl = fmaxf(logf(p), 0.f);
        float nl = (n > 0.f) ? fmaxf(logf(n), 0.f) : 0.f;
        acc += pl + nl;
    }
    #pragma unroll
    for (int m = 1; m < 64; m <<= 1) acc += __shfl_xor(acc, m);
    __shared__ float w4[4];
    if ((t & 63) == 0) w4[t >> 6] = acc;
    __syncthreads();
    if (t == 0) out[0] = (w4[0] + w4[1] + w4[2] + w4[3]) / (float)B_N;
}

// ------------------------------------------------------------------ entry ----
extern "C" void kernel_launch(void* const* d_in, const int* in_sizes, int n_in,
                              void* d_out, int out_size, void* d_ws, size_t ws_size,
                              hipStream_t stream) {
    const float* outputs = (const float*)d_in[0];
    const float* labels  = (const float*)d_in[1];
    float* out = (float*)d_out;
    char* ws = (char*)d_ws;
    __hip_bfloat16* Ob = (__hip_bfloat16*)(ws);
    __hip_bfloat16* Ln = (__hip_bfloat16*)(ws + 4194304);
    float* sq          = (float*)(ws + 6291456);
    float* pos_sums    = (float*)(ws + 6324224);
    float* neg_sums    = (float*)(ws + 6356992);
    unsigned* stats    = (unsigned*)(ws + 6389760);
    unsigned* simT     = (unsigned*)(ws + 6389824);
    unsigned* eudT     = (unsigned*)(ws + 74547264);
    int big = (ws_size >= WS_NEEDED) ? 1 : 0;

    prep_kernel<<<B_N / 4, 256, 0, stream>>>(outputs, labels, Ob, Ln, sq,
                                             pos_sums, neg_sums, stats);
    stats_kernel<<<NTRI, 256, 0, stream>>>(Ln, Ob, sq, stats, simT, eudT, big);
    if (big)
        loss_stream_kernel<<<NTRI, 256, 0, stream>>>(simT, eudT, stats,
                                                     pos_sums, neg_sums);
    else
        loss_recompute_kernel<<<NTRI, 256, 0, stream>>>(Ln, Ob, sq, stats,
                                                        pos_sums, neg_sums);
    finalize_kernel<<<1, 256, 0, stream>>>(pos_sums, neg_sums, out);
}